// Round 15
// baseline (2773.073 us; speedup 1.0000x reference)
//
#include <hip/hip_runtime.h>
#include <math.h>

// ---------------------------------------------------------------------------
// 2-layer LSTM, B=64 T=512 I=256 H=768, fp32 in/out.
// Round 15: r14 architecture (persistent + hierarchical flag aggregation)
// with two producer/burst latency cuts:
//  1. Per-wave packed u16 flags posted right after each wave's own vmcnt(0)
//     ack (pre-barrier) -- removes {barrier + tid0 store} from the chain.
//     Aggregator scans 192 packed u64s tight, posts one super-flag.
//  2. Contiguous 16B ring quanta [slot][ws][b] = 8 units of (ws,b):
//     consumer fragment = 2 ADJACENT u64 loads (halves lines touched).
// Weights in LDS. fp16 MFMA 16x16x32, fragment-major operands.
// ---------------------------------------------------------------------------

#define B_   64
#define T_   512
#define I_   256
#define H_   768
#define G4H  3072

constexpr size_t BTH = (size_t)B_ * T_ * H_;   // 25165824
constexpr size_t BH  = (size_t)B_ * H_;        // 49152

using f16_t = _Float16;
using f16x8 = __attribute__((ext_vector_type(8))) _Float16;
using f32x4 = __attribute__((ext_vector_type(4))) float;
typedef unsigned long long u64;

#define MFMA(a, b, c) __builtin_amdgcn_mfma_f32_16x16x32_f16((a), (b), (c), 0, 0, 0)

// Ring: quantum 16B = 8 f16 units of (ws, b). addr = slot*98304 + ws*1024 + b*16.
#define SLOT_STRIDE 98304    // 96*64*16 bytes
#define RING_SLOTS  16
#define RING_BYTES  (RING_SLOTS * SLOT_STRIDE)

// Per-wave packed flags: entry[t][ws] = 16B = 8 x u16 (one per wave, tag t+1).
constexpr size_t WF_BYTES = (size_t)T_ * 96 * 16;   // 768 KB per layer

// LDS partition (bytes): WL 0..98304 | pre 98304..132096 | bsL ..132224
#define SMEM_BYTES 132224

// ---------------------------------------------------------------------------
__global__ void k_packW(const float* __restrict__ src, f16_t* __restrict__ dst,
                        int K, int KC, int total) {
  int i = blockIdx.x * blockDim.x + threadIdx.x;
  int stride = gridDim.x * blockDim.x;
  for (; i < total; i += stride) {
    int e = i & 7;
    int lane = (i >> 3) & 63;
    int rest = i >> 9;          // ptile*KC + kc
    int kc = rest % KC;
    int ptile = rest / KC;
    int p = ptile * 16 + (lane & 15);
    int k = kc * 32 + (lane >> 4) * 8 + e;
    int r = (p & 3) * H_ + (p >> 2);
    dst[i] = (f16_t)src[(size_t)r * K + k];
  }
}

__global__ void k_packX(const float* __restrict__ x, f16_t* __restrict__ dst) {
  int i = blockIdx.x * blockDim.x + threadIdx.x;
  int stride = gridDim.x * blockDim.x;
  const int total = 4 * T_ * 8 * 64 * 8;  // 8,388,608
  for (; i < total; i += stride) {
    int e = i & 7;
    int lane = (i >> 3) & 63;
    int kc = (i >> 9) & 7;
    int t = (i >> 12) & 511;
    int mtile = i >> 21;
    int b = mtile * 16 + (lane & 15);
    int k = kc * 32 + (lane >> 4) * 8 + e;
    dst[i] = (f16_t)x[((size_t)b * T_ + t) * I_ + k];
  }
}

__global__ void k_bias(const float* __restrict__ bih, const float* __restrict__ bhh,
                       float* __restrict__ bsum) {
  int p = blockIdx.x * blockDim.x + threadIdx.x;
  if (p < G4H) {
    int r = (p & 3) * H_ + (p >> 2);
    bsum[p] = bih[r] + bhh[r];
  }
}

// Grid-stride zero (full coverage regardless of grid size).
__global__ void k_zero(int4* __restrict__ d, int n) {
  int stride = gridDim.x * blockDim.x;
  for (int i = blockIdx.x * blockDim.x + threadIdx.x; i < n; i += stride)
    d[i] = make_int4(0, 0, 0, 0);
}

__device__ __forceinline__ float sigf(float v) {
  return __builtin_amdgcn_rcpf(1.0f + __builtin_amdgcn_exp2f(v * -1.44269504f));
}
__device__ __forceinline__ float tanhf_fast(float v) {
  return 2.0f * __builtin_amdgcn_rcpf(1.0f + __builtin_amdgcn_exp2f(v * -2.88539008f)) - 1.0f;
}

__device__ __forceinline__ u64 ld_q(const u64* p) {
  return __hip_atomic_load(p, __ATOMIC_RELAXED, __HIP_MEMORY_SCOPE_AGENT);
}
__device__ __forceinline__ unsigned ld_flag(const int* p) {
  return (unsigned)__hip_atomic_load(p, __ATOMIC_RELAXED, __HIP_MEMORY_SCOPE_AGENT);
}

// Single-line super-flag spin (wave-uniform address -> 1 transaction/round).
__device__ __forceinline__ void wait_super(const int* p, unsigned tagv) {
  for (;;) {
    if (ld_flag(p) == tagv) return;
    __builtin_amdgcn_s_sleep(1);
  }
}

// One-shot burst (flag-guaranteed): fragment (chunk i, mtile) = 2 ADJACENT
// u64 loads (16B quantum), assemble f16x8, MFMA.
template <int KCW>
__device__ __forceinline__ void load_mfma(const char* sb, const int (&bA)[KCW],
                                          const f16_t* wl0, const f16_t* wl1,
                                          f32x4& a00, f32x4& a01, f32x4& a10,
                                          f32x4& a11) {
  u64 vA[KCW][2], vB[KCW][2];
#pragma unroll
  for (int i = 0; i < KCW; ++i) {
    const u64* p = (const u64*)(sb + bA[i]);
    vA[i][0] = ld_q(p);        // mtile m0, units 0-3
    vA[i][1] = ld_q(p + 1);    // mtile m0, units 4-7
    vB[i][0] = ld_q(p + 32);   // mtile m0+1 (+256B)
    vB[i][1] = ld_q(p + 33);
  }
#pragma unroll
  for (int i = 0; i < KCW; ++i) {
    union { u64 q[2]; f16x8 f; } cA, cB;
    cA.q[0] = vA[i][0]; cA.q[1] = vA[i][1];
    cB.q[0] = vB[i][0]; cB.q[1] = vB[i][1];
    f16x8 w0 = *(const f16x8*)(wl0 + (size_t)i * 512);
    f16x8 w1 = *(const f16x8*)(wl1 + (size_t)i * 512);
    a00 = MFMA(cA.f, w0, a00);
    a01 = MFMA(cA.f, w1, a01);
    a10 = MFMA(cB.f, w0, a10);
    a11 = MFMA(cB.f, w1, a11);
  }
}

// ---------------------------------------------------------------------------
// Aggregator (one wave): detect all 96 WGs x 8 waves done (192 packed u64s,
// 3 per lane, tight spin), then post super[t] = t+1.
__device__ __forceinline__ void run_agg(const u64* __restrict__ wf,
                                        int* __restrict__ sup) {
  if ((threadIdx.x >> 6) != 0) return;   // wave 0 only
  const int lane = threadIdx.x & 63;
  for (int t = 0; t < T_; ++t) {
    const u64* f = wf + (size_t)t * 192;
    const u64 want = (u64)(unsigned)(t + 1) * 0x0001000100010001ULL;
    for (;;) {
      u64 a = ld_q(f + lane);
      u64 b = ld_q(f + 64 + lane);
      u64 c = ld_q(f + 128 + lane);
      if (__all((int)((a == want) & (b == want) & (c == want)))) break;
    }
    if (lane == 0)
      __hip_atomic_store(sup + (size_t)t * 4, t + 1, __ATOMIC_RELAXED,
                         __HIP_MEMORY_SCOPE_AGENT);
  }
}

// ---------------------------------------------------------------------------
// Persistent per-layer loop (r14 structure). 8 waves = mg(2) x kg(4);
// wave = 2x2 tile. L0: kg0 = x-GEMM (+ mg1: super1[t-16] ring guard);
// kg1-3 consume h0[t-1]. L1: kg0-1 consume h0[t], kg2-3 consume h1[t-1].
// Consumer release = super-flags; per-wave packed flags feed aggregators.
template <int KCW, bool IS_L1>
__device__ __forceinline__ void run_layer(
    int ws, const f16_t* __restrict__ Xf, const f16_t* __restrict__ Wihf,
    const f16_t* __restrict__ Whhf, const float* __restrict__ bsum,
    char* __restrict__ ring0c, char* __restrict__ ring1c,
    u64* __restrict__ wf0, u64* __restrict__ wf1,
    int* __restrict__ sup0, int* __restrict__ sup1,
    float* __restrict__ out, char* smem) {
  f16_t* WL = (f16_t*)smem;                              // [4 kg][2 p][KCW][512]
  float (*pre)[64][33] = (float (*)[64][33])(smem + 98304);
  float* bsL = (float*)(smem + 132096);                  // [32]

  const int tid = threadIdx.x;
  const int wave = tid >> 6, lane = tid & 63;
  const int kg = wave & 3, mg = wave >> 2;
  const int laneo = lane * 8;
  const int pt0 = ws * 2, m0 = mg * 2;
  const int l15 = lane & 15, l4 = lane >> 4;

  if (tid < 32) bsL[tid] = bsum[ws * 32 + tid];

  // ---- stage W into LDS (mg==0 waves) ----
  if (mg == 0) {
    const f16_t* src;
    int KC, kc0;
    if constexpr (!IS_L1) {
      if (kg == 0) { src = Wihf; KC = 8;  kc0 = 0; }
      else         { src = Whhf; KC = 24; kc0 = (kg - 1) * 8; }
    } else {
      if (kg < 2)  { src = Wihf; KC = 24; kc0 = kg * 12; }
      else         { src = Whhf; KC = 24; kc0 = (kg - 2) * 12; }
    }
#pragma unroll
    for (int p = 0; p < 2; ++p)
#pragma unroll
      for (int i = 0; i < KCW; ++i)
        *(uint4*)(WL + ((size_t)((kg * 2 + p) * KCW + i)) * 512 + laneo) =
            *(const uint4*)(src + ((size_t)(pt0 + p) * KC + kc0 + i) * 512 + laneo);
  }

  // Consumer chunk start (32-unit chunks of the source h vector).
  int kcs = 0;
  if constexpr (!IS_L1) kcs = (kg - 1) * 8;      // valid for kg>=1
  else                  kcs = (kg < 2) ? kg * 12 : (kg - 2) * 12;

  // Byte offset of chunk i's quantum: producer ws'=(kcs+i)*4+l4,
  // batch row = m0*16+l15, 16B quanta.
  int bA[KCW];
#pragma unroll
  for (int i = 0; i < KCW; ++i)
    bA[i] = ((kcs + i) * 4 + l4) * 1024 + (m0 * 16 + l15) * 16;

  float c_reg = 0.f;
  const int u = tid & 7, b = tid >> 3;
  const int j = ws * 8 + u;
  char* myringc = IS_L1 ? ring1c : ring0c;
  u64* mywf = IS_L1 ? wf1 : wf0;
  const f16_t* wl0 = WL + (size_t)(kg * 2) * KCW * 512 + laneo;
  const f16_t* wl1 = wl0 + (size_t)KCW * 512;

  __syncthreads();

  for (int t = 0; t < T_; ++t) {
    f32x4 a00 = {0.f, 0.f, 0.f, 0.f};
    f32x4 a01 = {0.f, 0.f, 0.f, 0.f};
    f32x4 a10 = {0.f, 0.f, 0.f, 0.f};
    f32x4 a11 = {0.f, 0.f, 0.f, 0.f};

    if constexpr (!IS_L1) {
      if (kg == 0) {
        // ring guard: before publishing h0[t] over h0[t-16]'s slot, all L1
        // WGs must be past step t-16 (single super-flag check, off-path).
        if (mg == 1 && t >= RING_SLOTS)
          wait_super(sup1 + (size_t)(t - RING_SLOTS) * 4,
                     (unsigned)(t - RING_SLOTS + 1));
        // x_t @ Wih0^T (no recurrence dependency)
        const f16_t* A0 = Xf + ((size_t)m0 * T_ + t) * 4096 + laneo;
        const f16_t* A1 = A0 + (size_t)T_ * 4096;
#pragma unroll
        for (int i = 0; i < KCW; ++i) {
          f16x8 x0 = *(const f16x8*)(A0 + (size_t)i * 512);
          f16x8 x1 = *(const f16x8*)(A1 + (size_t)i * 512);
          f16x8 w0 = *(const f16x8*)(wl0 + (size_t)i * 512);
          f16x8 w1 = *(const f16x8*)(wl1 + (size_t)i * 512);
          a00 = MFMA(x0, w0, a00);
          a01 = MFMA(x0, w1, a01);
          a10 = MFMA(x1, w0, a10);
          a11 = MFMA(x1, w1, a11);
        }
      } else if (t >= 1) {
        wait_super(sup0 + (size_t)(t - 1) * 4, (unsigned)t);
        const char* sb = ring0c + (size_t)((t - 1) & (RING_SLOTS - 1)) * SLOT_STRIDE;
        load_mfma<KCW>(sb, bA, wl0, wl1, a00, a01, a10, a11);
      }
    } else {
      const int srcstep = (kg < 2) ? t : t - 1;
      if (srcstep >= 0) {
        const unsigned tg = (unsigned)(srcstep + 1);
        wait_super(((kg < 2) ? sup0 : sup1) + (size_t)srcstep * 4, tg);
        const char* sb = ((kg < 2) ? ring0c : ring1c) +
                         (size_t)(srcstep & (RING_SLOTS - 1)) * SLOT_STRIDE;
        load_mfma<KCW>(sb, bA, wl0, wl1, a00, a01, a10, a11);
      }
    }

    // ---- partial-sum exchange (C layout: col=lane&15, row=l4*4+r) ----
#pragma unroll
    for (int r = 0; r < 4; ++r) {
      pre[kg][m0 * 16 + l4 * 4 + r][l15]           = a00[r];
      pre[kg][m0 * 16 + l4 * 4 + r][16 + l15]      = a01[r];
      pre[kg][m0 * 16 + 16 + l4 * 4 + r][l15]      = a10[r];
      pre[kg][m0 * 16 + 16 + l4 * 4 + r][16 + l15] = a11[r];
    }
    __syncthreads();

    // ---- gate phase: thread = (u = tid&7, b = tid>>3) ----
    float h;
    {
      float g0 = pre[0][b][4 * u + 0] + pre[1][b][4 * u + 0] + pre[2][b][4 * u + 0] + pre[3][b][4 * u + 0] + bsL[4 * u + 0];
      float g1 = pre[0][b][4 * u + 1] + pre[1][b][4 * u + 1] + pre[2][b][4 * u + 1] + pre[3][b][4 * u + 1] + bsL[4 * u + 1];
      float g2 = pre[0][b][4 * u + 2] + pre[1][b][4 * u + 2] + pre[2][b][4 * u + 2] + pre[3][b][4 * u + 2] + bsL[4 * u + 2];
      float g3 = pre[0][b][4 * u + 3] + pre[1][b][4 * u + 3] + pre[2][b][4 * u + 3] + pre[3][b][4 * u + 3] + bsL[4 * u + 3];
      float ig = sigf(g0), fg = sigf(g1), gg = tanhf_fast(g2), og = sigf(g3);
      c_reg = fg * c_reg + ig * gg;
      h = og * tanhf_fast(c_reg);

      // ring publish: gather all 8 units of batch b via shfl; u==0 threads
      // store the 16B quantum as 2 adjacent u64 atomic stores.
      unsigned hb = (unsigned)__builtin_bit_cast(unsigned short, (f16_t)h);
      const int gbase = lane & ~7;
      unsigned s0 = (unsigned)__shfl((int)hb, gbase + 0);
      unsigned s1 = (unsigned)__shfl((int)hb, gbase + 1);
      unsigned s2 = (unsigned)__shfl((int)hb, gbase + 2);
      unsigned s3 = (unsigned)__shfl((int)hb, gbase + 3);
      unsigned s4 = (unsigned)__shfl((int)hb, gbase + 4);
      unsigned s5 = (unsigned)__shfl((int)hb, gbase + 5);
      unsigned s6 = (unsigned)__shfl((int)hb, gbase + 6);
      unsigned s7 = (unsigned)__shfl((int)hb, gbase + 7);
      if (u == 0) {
        u64 lo = (u64)(s0 | (s1 << 16)) | ((u64)(s2 | (s3 << 16)) << 32);
        u64 hi = (u64)(s4 | (s5 << 16)) | ((u64)(s6 | (s7 << 16)) << 32);
        u64* dst = (u64*)(myringc +
                          (size_t)(t & (RING_SLOTS - 1)) * SLOT_STRIDE +
                          (size_t)ws * 1024 + (size_t)b * 16);
        __hip_atomic_store(dst,     lo, __ATOMIC_RELAXED, __HIP_MEMORY_SCOPE_AGENT);
        __hip_atomic_store(dst + 1, hi, __ATOMIC_RELAXED, __HIP_MEMORY_SCOPE_AGENT);
      }
    }
    // per-wave ack of own ring stores, then per-wave packed flag (PRE-barrier
    // -- removes {barrier + tid0 store} from the publish->aggregator chain).
    asm volatile("s_waitcnt vmcnt(0)" ::: "memory");
    if (lane == 0) {
      unsigned short* fp =
          (unsigned short*)((char*)mywf + ((size_t)t * 96 + ws) * 16) + wave;
      __hip_atomic_store(fp, (unsigned short)(t + 1), __ATOMIC_RELAXED,
                         __HIP_MEMORY_SCOPE_AGENT);
    }

    // ---- deferred outputs (off critical path) ----
    if constexpr (IS_L1) {
      out[((size_t)b * T_ + t) * H_ + j] = h;  // ys
      if (t == T_ - 1) {
        out[BTH + BH + (size_t)b * H_ + j] = h;
        out[BTH + 3 * BH + (size_t)b * H_ + j] = c_reg;
      }
    } else {
      if (t == T_ - 1) {
        out[BTH + (size_t)b * H_ + j] = h;
        out[BTH + 2 * BH + (size_t)b * H_ + j] = c_reg;
      }
    }
    __syncthreads();   // pre[] of t reusable for t+1
  }
}

__launch_bounds__(512, 1)
__global__ void k_lstm(const f16_t* __restrict__ Xf,
                       const f16_t* __restrict__ Wih0f, const f16_t* __restrict__ Whh0f,
                       const f16_t* __restrict__ Wih1f, const f16_t* __restrict__ Whh1f,
                       const float* __restrict__ bsum0, const float* __restrict__ bsum1,
                       char* __restrict__ ring0c, char* __restrict__ ring1c,
                       u64* __restrict__ wf0, u64* __restrict__ wf1,
                       int* __restrict__ sup0, int* __restrict__ sup1,
                       float* __restrict__ out) {
  extern __shared__ char smem[];
  const int wg = blockIdx.x;
  if (wg < 96)
    run_layer<8, false>(wg, Xf, Wih0f, Whh0f, bsum0, ring0c, ring1c,
                        wf0, wf1, sup0, sup1, out, smem);
  else if (wg < 192)
    run_layer<12, true>(wg - 96, Xf, Wih1f, Whh1f, bsum1, ring0c, ring1c,
                        wf0, wf1, sup0, sup1, out, smem);
  else if (wg == 192)
    run_agg(wf0, sup0);
  else
    run_agg(wf1, sup1);
}

// ---------------------------------------------------------------------------
extern "C" void kernel_launch(void* const* d_in, const int* in_sizes, int n_in,
                              void* d_out, int out_size, void* d_ws, size_t ws_size,
                              hipStream_t stream) {
  const float* x    = (const float*)d_in[0];
  const float* wih0 = (const float*)d_in[1];
  const float* whh0 = (const float*)d_in[2];
  const float* bih0 = (const float*)d_in[3];
  const float* bhh0 = (const float*)d_in[4];
  const float* wih1 = (const float*)d_in[5];
  const float* whh1 = (const float*)d_in[6];
  const float* bih1 = (const float*)d_in[7];
  const float* bhh1 = (const float*)d_in[8];
  float* out = (float*)d_out;

  char* base = (char*)d_ws;
  size_t off = 0;
  auto take = [&](size_t bytes) -> char* {
    char* r = base + off;
    off = (off + bytes + 255) & ~(size_t)255;
    return r;
  };
  f16_t* Wih0f = (f16_t*)take((size_t)G4H * I_ * 2);
  f16_t* Whh0f = (f16_t*)take((size_t)G4H * H_ * 2);
  f16_t* Wih1f = (f16_t*)take((size_t)G4H * H_ * 2);
  f16_t* Whh1f = (f16_t*)take((size_t)G4H * H_ * 2);
  f16_t* Xf    = (f16_t*)take((size_t)4 * T_ * 8 * 64 * 8 * 2);
  float* bsum0 = (float*)take((size_t)G4H * 4);
  float* bsum1 = (float*)take((size_t)G4H * 4);
  // rings (flag-gated; no zero needed) + per-wave flags + super-flags (zeroed)
  char* ring0c = take(RING_BYTES);
  char* ring1c = take(RING_BYTES);
  const size_t supBytes = (size_t)T_ * 16;               // 8 KB each
  char* fl = take(2 * WF_BYTES + 2 * supBytes);
  u64* wf0 = (u64*)fl;
  u64* wf1 = (u64*)(fl + WF_BYTES);
  int* sup0 = (int*)(fl + 2 * WF_BYTES);
  int* sup1 = sup0 + (size_t)T_ * 4;
  const size_t zeroBytes = 2 * WF_BYTES + 2 * supBytes;

  hipFuncSetAttribute(reinterpret_cast<const void*>(k_lstm),
                      hipFuncAttributeMaxDynamicSharedMemorySize, SMEM_BYTES);

  k_packW<<<768, 256, 0, stream>>>(wih0, Wih0f, I_, 8, G4H * I_);
  k_packW<<<2048, 256, 0, stream>>>(whh0, Whh0f, H_, 24, G4H * H_);
  k_packW<<<2048, 256, 0, stream>>>(wih1, Wih1f, H_, 24, G4H * H_);
  k_packW<<<2048, 256, 0, stream>>>(whh1, Whh1f, H_, 24, G4H * H_);
  k_packX<<<4096, 256, 0, stream>>>(x, Xf);
  k_bias<<<12, 256, 0, stream>>>(bih0, bhh0, bsum0);
  k_bias<<<12, 256, 0, stream>>>(bih1, bhh1, bsum1);
  k_zero<<<520, 256, 0, stream>>>((int4*)fl, (int)(zeroBytes / 16));

  k_lstm<<<194, 512, SMEM_BYTES, stream>>>(Xf, Wih0f, Whh0f, Wih1f, Whh1f,
                                           bsum0, bsum1, ring0c, ring1c,
                                           wf0, wf1, sup0, sup1, out);
}

// Round 16
// 2431.823 us; speedup vs baseline: 1.1403x; 1.1403x over previous
//
#include <hip/hip_runtime.h>
#include <math.h>

// ---------------------------------------------------------------------------
// 2-layer LSTM, B=64 T=512 I=256 H=768, fp32 in/out.
// Round 16: r14 architecture EXACTLY (persistent + hierarchical flag
// aggregation, per-WG single-writer flags posted by tid0 after barrier)
// + r15's contiguous 16B ring quanta ONLY (single-variable test):
// ring [slot][ws][b] 16B = 8 units of (ws,b); consumer fragment = 2
// ADJACENT u64 loads (1 line vs r14's 2). r15's packed u16 multi-writer
// flag entries are REVERTED (they cost +120MB WRITE and +25% time).
// Weights in LDS. fp16 MFMA 16x16x32, fragment-major operands.
// ---------------------------------------------------------------------------

#define B_   64
#define T_   512
#define I_   256
#define H_   768
#define G4H  3072

constexpr size_t BTH = (size_t)B_ * T_ * H_;   // 25165824
constexpr size_t BH  = (size_t)B_ * H_;        // 49152

using f16_t = _Float16;
using f16x8 = __attribute__((ext_vector_type(8))) _Float16;
using f32x4 = __attribute__((ext_vector_type(4))) float;
typedef unsigned long long u64;

#define MFMA(a, b, c) __builtin_amdgcn_mfma_f32_16x16x32_f16((a), (b), (c), 0, 0, 0)

// Ring: quantum 16B = 8 f16 units of (ws, b). addr = slot*98304 + ws*1024 + b*16.
#define SLOT_STRIDE 98304    // 96*64*16 bytes
#define RING_SLOTS  16
#define RING_BYTES  (RING_SLOTS * SLOT_STRIDE)

// LDS partition (bytes): WL 0..98304 | pre 98304..132096 | bsL ..132224
#define SMEM_BYTES 132224

// ---------------------------------------------------------------------------
__global__ void k_packW(const float* __restrict__ src, f16_t* __restrict__ dst,
                        int K, int KC, int total) {
  int i = blockIdx.x * blockDim.x + threadIdx.x;
  int stride = gridDim.x * blockDim.x;
  for (; i < total; i += stride) {
    int e = i & 7;
    int lane = (i >> 3) & 63;
    int rest = i >> 9;          // ptile*KC + kc
    int kc = rest % KC;
    int ptile = rest / KC;
    int p = ptile * 16 + (lane & 15);
    int k = kc * 32 + (lane >> 4) * 8 + e;
    int r = (p & 3) * H_ + (p >> 2);
    dst[i] = (f16_t)src[(size_t)r * K + k];
  }
}

__global__ void k_packX(const float* __restrict__ x, f16_t* __restrict__ dst) {
  int i = blockIdx.x * blockDim.x + threadIdx.x;
  int stride = gridDim.x * blockDim.x;
  const int total = 4 * T_ * 8 * 64 * 8;  // 8,388,608
  for (; i < total; i += stride) {
    int e = i & 7;
    int lane = (i >> 3) & 63;
    int kc = (i >> 9) & 7;
    int t = (i >> 12) & 511;
    int mtile = i >> 21;
    int b = mtile * 16 + (lane & 15);
    int k = kc * 32 + (lane >> 4) * 8 + e;
    dst[i] = (f16_t)x[((size_t)b * T_ + t) * I_ + k];
  }
}

__global__ void k_bias(const float* __restrict__ bih, const float* __restrict__ bhh,
                       float* __restrict__ bsum) {
  int p = blockIdx.x * blockDim.x + threadIdx.x;
  if (p < G4H) {
    int r = (p & 3) * H_ + (p >> 2);
    bsum[p] = bih[r] + bhh[r];
  }
}

// Grid-stride zero (full coverage regardless of grid size).
__global__ void k_zero(int4* __restrict__ d, int n) {
  int stride = gridDim.x * blockDim.x;
  for (int i = blockIdx.x * blockDim.x + threadIdx.x; i < n; i += stride)
    d[i] = make_int4(0, 0, 0, 0);
}

__device__ __forceinline__ float sigf(float v) {
  return __builtin_amdgcn_rcpf(1.0f + __builtin_amdgcn_exp2f(v * -1.44269504f));
}
__device__ __forceinline__ float tanhf_fast(float v) {
  return 2.0f * __builtin_amdgcn_rcpf(1.0f + __builtin_amdgcn_exp2f(v * -2.88539008f)) - 1.0f;
}

__device__ __forceinline__ u64 ld_q(const u64* p) {
  return __hip_atomic_load(p, __ATOMIC_RELAXED, __HIP_MEMORY_SCOPE_AGENT);
}
__device__ __forceinline__ unsigned ld_flag(const int* p) {
  return (unsigned)__hip_atomic_load(p, __ATOMIC_RELAXED, __HIP_MEMORY_SCOPE_AGENT);
}

// Single-line super-flag spin (wave-uniform address -> 1 transaction/round).
__device__ __forceinline__ void wait_super(const int* p, unsigned tagv) {
  for (;;) {
    if (ld_flag(p) == tagv) return;
    __builtin_amdgcn_s_sleep(1);
  }
}

// One-shot burst (flag-guaranteed): fragment (chunk i, mtile) = 2 ADJACENT
// u64 loads (one 16B quantum), assemble f16x8, MFMA.
template <int KCW>
__device__ __forceinline__ void load_mfma(const char* sb, const int (&bA)[KCW],
                                          const f16_t* wl0, const f16_t* wl1,
                                          f32x4& a00, f32x4& a01, f32x4& a10,
                                          f32x4& a11) {
  u64 vA[KCW][2], vB[KCW][2];
#pragma unroll
  for (int i = 0; i < KCW; ++i) {
    const u64* p = (const u64*)(sb + bA[i]);
    vA[i][0] = ld_q(p);        // mtile m0, units 0-3
    vA[i][1] = ld_q(p + 1);    // mtile m0, units 4-7
    vB[i][0] = ld_q(p + 32);   // mtile m0+1 (+256B)
    vB[i][1] = ld_q(p + 33);
  }
#pragma unroll
  for (int i = 0; i < KCW; ++i) {
    union { u64 q[2]; f16x8 f; } cA, cB;
    cA.q[0] = vA[i][0]; cA.q[1] = vA[i][1];
    cB.q[0] = vB[i][0]; cB.q[1] = vB[i][1];
    f16x8 w0 = *(const f16x8*)(wl0 + (size_t)i * 512);
    f16x8 w1 = *(const f16x8*)(wl1 + (size_t)i * 512);
    a00 = MFMA(cA.f, w0, a00);
    a01 = MFMA(cA.f, w1, a01);
    a10 = MFMA(cB.f, w0, a10);
    a11 = MFMA(cB.f, w1, a11);
  }
}

// ---------------------------------------------------------------------------
// Aggregator (one wave): for each t, detect all 96 per-WG flags == t+1, then
// post super[t] = t+1. Dedicated -> tight spin (no sleep) for fastest detect.
__device__ __forceinline__ void run_agg(const int* __restrict__ flags,
                                        int* __restrict__ sup) {
  if ((threadIdx.x >> 6) != 0) return;   // wave 0 only
  const int lane = threadIdx.x & 63;
  for (int t = 0; t < T_; ++t) {
    const int* f = flags + (size_t)t * 128 * 4;
    const unsigned want = (unsigned)(t + 1);
    for (;;) {
      unsigned v0 = ld_flag(f + lane * 4);
      unsigned v1 = (lane < 32) ? ld_flag(f + (64 + lane) * 4) : want;
      if (__all((v0 == want) & (v1 == want))) break;
    }
    asm volatile("s_waitcnt vmcnt(0)" ::: "memory");
    if (lane == 0)
      __hip_atomic_store(sup + (size_t)t * 4, (int)want, __ATOMIC_RELAXED,
                         __HIP_MEMORY_SCOPE_AGENT);
  }
}

// ---------------------------------------------------------------------------
// Persistent per-layer loop (r14 structure). 8 waves = mg(2) x kg(4);
// wave = 2x2 tile. L0: kg0 = x-GEMM (+ mg1: super1[t-16] ring guard);
// kg1-3 consume h0[t-1]. L1: kg0-1 consume h0[t], kg2-3 consume h1[t-1].
// Consumer release = super-flags; per-WG flags (single writer, one store,
// posted by tid0 after the barrier) feed only the aggregators.
template <int KCW, bool IS_L1>
__device__ __forceinline__ void run_layer(
    int ws, const f16_t* __restrict__ Xf, const f16_t* __restrict__ Wihf,
    const f16_t* __restrict__ Whhf, const float* __restrict__ bsum,
    char* __restrict__ ring0c, char* __restrict__ ring1c,
    int* __restrict__ flag0, int* __restrict__ flag1,
    int* __restrict__ sup0, int* __restrict__ sup1,
    float* __restrict__ out, char* smem) {
  f16_t* WL = (f16_t*)smem;                              // [4 kg][2 p][KCW][512]
  float (*pre)[64][33] = (float (*)[64][33])(smem + 98304);
  float* bsL = (float*)(smem + 132096);                  // [32]

  const int tid = threadIdx.x;
  const int wave = tid >> 6, lane = tid & 63;
  const int kg = wave & 3, mg = wave >> 2;
  const int laneo = lane * 8;
  const int pt0 = ws * 2, m0 = mg * 2;
  const int l15 = lane & 15, l4 = lane >> 4;

  if (tid < 32) bsL[tid] = bsum[ws * 32 + tid];

  // ---- stage W into LDS (mg==0 waves) ----
  if (mg == 0) {
    const f16_t* src;
    int KC, kc0;
    if constexpr (!IS_L1) {
      if (kg == 0) { src = Wihf; KC = 8;  kc0 = 0; }
      else         { src = Whhf; KC = 24; kc0 = (kg - 1) * 8; }
    } else {
      if (kg < 2)  { src = Wihf; KC = 24; kc0 = kg * 12; }
      else         { src = Whhf; KC = 24; kc0 = (kg - 2) * 12; }
    }
#pragma unroll
    for (int p = 0; p < 2; ++p)
#pragma unroll
      for (int i = 0; i < KCW; ++i)
        *(uint4*)(WL + ((size_t)((kg * 2 + p) * KCW + i)) * 512 + laneo) =
            *(const uint4*)(src + ((size_t)(pt0 + p) * KC + kc0 + i) * 512 + laneo);
  }

  // Consumer chunk start (32-unit chunks of the source h vector).
  int kcs = 0;
  if constexpr (!IS_L1) kcs = (kg - 1) * 8;      // valid for kg>=1
  else                  kcs = (kg < 2) ? kg * 12 : (kg - 2) * 12;

  // Byte offset of chunk i's quantum: producer ws'=(kcs+i)*4+l4,
  // batch row = m0*16+l15, 16B contiguous quanta.
  int bA[KCW];
#pragma unroll
  for (int i = 0; i < KCW; ++i)
    bA[i] = ((kcs + i) * 4 + l4) * 1024 + (m0 * 16 + l15) * 16;

  float c_reg = 0.f;
  const int u = tid & 7, b = tid >> 3;
  const int j = ws * 8 + u;
  char* myringc = IS_L1 ? ring1c : ring0c;
  int* myflag = IS_L1 ? flag1 : flag0;
  const f16_t* wl0 = WL + (size_t)(kg * 2) * KCW * 512 + laneo;
  const f16_t* wl1 = wl0 + (size_t)KCW * 512;

  __syncthreads();

  for (int t = 0; t < T_; ++t) {
    f32x4 a00 = {0.f, 0.f, 0.f, 0.f};
    f32x4 a01 = {0.f, 0.f, 0.f, 0.f};
    f32x4 a10 = {0.f, 0.f, 0.f, 0.f};
    f32x4 a11 = {0.f, 0.f, 0.f, 0.f};

    if constexpr (!IS_L1) {
      if (kg == 0) {
        // ring guard: before publishing h0[t] over h0[t-16]'s slot, all L1
        // WGs must be past step t-16 (single super-flag check, off-path).
        if (mg == 1 && t >= RING_SLOTS)
          wait_super(sup1 + (size_t)(t - RING_SLOTS) * 4,
                     (unsigned)(t - RING_SLOTS + 1));
        // x_t @ Wih0^T (no recurrence dependency)
        const f16_t* A0 = Xf + ((size_t)m0 * T_ + t) * 4096 + laneo;
        const f16_t* A1 = A0 + (size_t)T_ * 4096;
#pragma unroll
        for (int i = 0; i < KCW; ++i) {
          f16x8 x0 = *(const f16x8*)(A0 + (size_t)i * 512);
          f16x8 x1 = *(const f16x8*)(A1 + (size_t)i * 512);
          f16x8 w0 = *(const f16x8*)(wl0 + (size_t)i * 512);
          f16x8 w1 = *(const f16x8*)(wl1 + (size_t)i * 512);
          a00 = MFMA(x0, w0, a00);
          a01 = MFMA(x0, w1, a01);
          a10 = MFMA(x1, w0, a10);
          a11 = MFMA(x1, w1, a11);
        }
      } else if (t >= 1) {
        wait_super(sup0 + (size_t)(t - 1) * 4, (unsigned)t);
        const char* sb = ring0c + (size_t)((t - 1) & (RING_SLOTS - 1)) * SLOT_STRIDE;
        load_mfma<KCW>(sb, bA, wl0, wl1, a00, a01, a10, a11);
      }
    } else {
      const int srcstep = (kg < 2) ? t : t - 1;
      if (srcstep >= 0) {
        const unsigned tg = (unsigned)(srcstep + 1);
        wait_super(((kg < 2) ? sup0 : sup1) + (size_t)srcstep * 4, tg);
        const char* sb = ((kg < 2) ? ring0c : ring1c) +
                         (size_t)(srcstep & (RING_SLOTS - 1)) * SLOT_STRIDE;
        load_mfma<KCW>(sb, bA, wl0, wl1, a00, a01, a10, a11);
      }
    }

    // ---- partial-sum exchange (C layout: col=lane&15, row=l4*4+r) ----
#pragma unroll
    for (int r = 0; r < 4; ++r) {
      pre[kg][m0 * 16 + l4 * 4 + r][l15]           = a00[r];
      pre[kg][m0 * 16 + l4 * 4 + r][16 + l15]      = a01[r];
      pre[kg][m0 * 16 + 16 + l4 * 4 + r][l15]      = a10[r];
      pre[kg][m0 * 16 + 16 + l4 * 4 + r][16 + l15] = a11[r];
    }
    __syncthreads();

    // ---- gate phase: thread = (u = tid&7, b = tid>>3) ----
    float h;
    {
      float g0 = pre[0][b][4 * u + 0] + pre[1][b][4 * u + 0] + pre[2][b][4 * u + 0] + pre[3][b][4 * u + 0] + bsL[4 * u + 0];
      float g1 = pre[0][b][4 * u + 1] + pre[1][b][4 * u + 1] + pre[2][b][4 * u + 1] + pre[3][b][4 * u + 1] + bsL[4 * u + 1];
      float g2 = pre[0][b][4 * u + 2] + pre[1][b][4 * u + 2] + pre[2][b][4 * u + 2] + pre[3][b][4 * u + 2] + bsL[4 * u + 2];
      float g3 = pre[0][b][4 * u + 3] + pre[1][b][4 * u + 3] + pre[2][b][4 * u + 3] + pre[3][b][4 * u + 3] + bsL[4 * u + 3];
      float ig = sigf(g0), fg = sigf(g1), gg = tanhf_fast(g2), og = sigf(g3);
      c_reg = fg * c_reg + ig * gg;
      h = og * tanhf_fast(c_reg);

      // ring publish: gather all 8 units of batch b via shfl; u==0 threads
      // store the 16B quantum as 2 adjacent u64 atomic stores.
      unsigned hb = (unsigned)__builtin_bit_cast(unsigned short, (f16_t)h);
      const int gbase = lane & ~7;
      unsigned s0 = (unsigned)__shfl((int)hb, gbase + 0);
      unsigned s1 = (unsigned)__shfl((int)hb, gbase + 1);
      unsigned s2 = (unsigned)__shfl((int)hb, gbase + 2);
      unsigned s3 = (unsigned)__shfl((int)hb, gbase + 3);
      unsigned s4 = (unsigned)__shfl((int)hb, gbase + 4);
      unsigned s5 = (unsigned)__shfl((int)hb, gbase + 5);
      unsigned s6 = (unsigned)__shfl((int)hb, gbase + 6);
      unsigned s7 = (unsigned)__shfl((int)hb, gbase + 7);
      if (u == 0) {
        u64 lo = (u64)(s0 | (s1 << 16)) | ((u64)(s2 | (s3 << 16)) << 32);
        u64 hi = (u64)(s4 | (s5 << 16)) | ((u64)(s6 | (s7 << 16)) << 32);
        u64* dst = (u64*)(myringc +
                          (size_t)(t & (RING_SLOTS - 1)) * SLOT_STRIDE +
                          (size_t)ws * 1024 + (size_t)b * 16);
        __hip_atomic_store(dst,     lo, __ATOMIC_RELAXED, __HIP_MEMORY_SCOPE_AGENT);
        __hip_atomic_store(dst + 1, hi, __ATOMIC_RELAXED, __HIP_MEMORY_SCOPE_AGENT);
      }
    }
    // per-wave ack of own ring stores (parallel across waves), then publish
    // via ONE single-writer flag store (r14's proven scheme).
    asm volatile("s_waitcnt vmcnt(0)" ::: "memory");
    __syncthreads();
    if (tid == 0)
      __hip_atomic_store(myflag + ((size_t)t * 128 + ws) * 4, t + 1,
                         __ATOMIC_RELAXED, __HIP_MEMORY_SCOPE_AGENT);

    // ---- deferred outputs (off critical path) ----
    if constexpr (IS_L1) {
      out[((size_t)b * T_ + t) * H_ + j] = h;  // ys
      if (t == T_ - 1) {
        out[BTH + BH + (size_t)b * H_ + j] = h;
        out[BTH + 3 * BH + (size_t)b * H_ + j] = c_reg;
      }
    } else {
      if (t == T_ - 1) {
        out[BTH + (size_t)b * H_ + j] = h;
        out[BTH + 2 * BH + (size_t)b * H_ + j] = c_reg;
      }
    }
  }
}

__launch_bounds__(512, 1)
__global__ void k_lstm(const f16_t* __restrict__ Xf,
                       const f16_t* __restrict__ Wih0f, const f16_t* __restrict__ Whh0f,
                       const f16_t* __restrict__ Wih1f, const f16_t* __restrict__ Whh1f,
                       const float* __restrict__ bsum0, const float* __restrict__ bsum1,
                       char* __restrict__ ring0c, char* __restrict__ ring1c,
                       int* __restrict__ flag0, int* __restrict__ flag1,
                       int* __restrict__ sup0, int* __restrict__ sup1,
                       float* __restrict__ out) {
  extern __shared__ char smem[];
  const int wg = blockIdx.x;
  if (wg < 96)
    run_layer<8, false>(wg, Xf, Wih0f, Whh0f, bsum0, ring0c, ring1c,
                        flag0, flag1, sup0, sup1, out, smem);
  else if (wg < 192)
    run_layer<12, true>(wg - 96, Xf, Wih1f, Whh1f, bsum1, ring0c, ring1c,
                        flag0, flag1, sup0, sup1, out, smem);
  else if (wg == 192)
    run_agg(flag0, sup0);
  else
    run_agg(flag1, sup1);
}

// ---------------------------------------------------------------------------
extern "C" void kernel_launch(void* const* d_in, const int* in_sizes, int n_in,
                              void* d_out, int out_size, void* d_ws, size_t ws_size,
                              hipStream_t stream) {
  const float* x    = (const float*)d_in[0];
  const float* wih0 = (const float*)d_in[1];
  const float* whh0 = (const float*)d_in[2];
  const float* bih0 = (const float*)d_in[3];
  const float* bhh0 = (const float*)d_in[4];
  const float* wih1 = (const float*)d_in[5];
  const float* whh1 = (const float*)d_in[6];
  const float* bih1 = (const float*)d_in[7];
  const float* bhh1 = (const float*)d_in[8];
  float* out = (float*)d_out;

  char* base = (char*)d_ws;
  size_t off = 0;
  auto take = [&](size_t bytes) -> char* {
    char* r = base + off;
    off = (off + bytes + 255) & ~(size_t)255;
    return r;
  };
  f16_t* Wih0f = (f16_t*)take((size_t)G4H * I_ * 2);
  f16_t* Whh0f = (f16_t*)take((size_t)G4H * H_ * 2);
  f16_t* Wih1f = (f16_t*)take((size_t)G4H * H_ * 2);
  f16_t* Whh1f = (f16_t*)take((size_t)G4H * H_ * 2);
  f16_t* Xf    = (f16_t*)take((size_t)4 * T_ * 8 * 64 * 8 * 2);
  float* bsum0 = (float*)take((size_t)G4H * 4);
  float* bsum1 = (float*)take((size_t)G4H * 4);
  // rings (flag-gated; no zero needed) + per-WG flags + super-flags (zeroed)
  char* ring0c = take(RING_BYTES);
  char* ring1c = take(RING_BYTES);
  const size_t flagBytes = (size_t)T_ * 128 * 16;        // 1 MB each
  const size_t supBytes  = (size_t)T_ * 16;              // 8 KB each
  char* fl = take(2 * flagBytes + 2 * supBytes);
  int* flag0 = (int*)fl;
  int* flag1 = flag0 + (size_t)T_ * 128 * 4;
  int* sup0  = flag1 + (size_t)T_ * 128 * 4;
  int* sup1  = sup0 + (size_t)T_ * 4;
  const size_t zeroBytes = 2 * flagBytes + 2 * supBytes;

  hipFuncSetAttribute(reinterpret_cast<const void*>(k_lstm),
                      hipFuncAttributeMaxDynamicSharedMemorySize, SMEM_BYTES);

  k_packW<<<768, 256, 0, stream>>>(wih0, Wih0f, I_, 8, G4H * I_);
  k_packW<<<2048, 256, 0, stream>>>(whh0, Whh0f, H_, 24, G4H * H_);
  k_packW<<<2048, 256, 0, stream>>>(wih1, Wih1f, H_, 24, G4H * H_);
  k_packW<<<2048, 256, 0, stream>>>(whh1, Whh1f, H_, 24, G4H * H_);
  k_packX<<<4096, 256, 0, stream>>>(x, Xf);
  k_bias<<<12, 256, 0, stream>>>(bih0, bhh0, bsum0);
  k_bias<<<12, 256, 0, stream>>>(bih1, bhh1, bsum1);
  k_zero<<<520, 256, 0, stream>>>((int4*)fl, (int)(zeroBytes / 16));

  k_lstm<<<194, 512, SMEM_BYTES, stream>>>(Xf, Wih0f, Whh0f, Wih1f, Whh1f,
                                           bsum0, bsum1, ring0c, ring1c,
                                           flag0, flag1, sup0, sup1, out);
}

// Round 17
// 2207.324 us; speedup vs baseline: 1.2563x; 1.1017x over previous
//
#include <hip/hip_runtime.h>
#include <math.h>

// ---------------------------------------------------------------------------
// 2-layer LSTM, B=64 T=512 I=256 H=768, fp32 in/out.
// Round 17: REVERT to r14 verbatim (proven best: 2.209 ms). r15 (packed
// multi-writer flags) and r16 (contiguous 16B quanta) both regressed; r14's
// configuration is the empirical optimum of the persistent+aggregated-flag
// architecture:
//  - Producers: ring u64 quanta (4 units each, q0/q1 512B apart) -> per-wave
//    vmcnt(0) ack -> barrier -> tid0 posts ONE per-WG flag.
//  - 2 aggregator WGs (one per layer) tight-spin the 96 per-WG flags and
//    post ONE super-flag per (layer, step). Consumers spin on a single
//    wave-uniform line, then ONE one-shot data burst.
//  - Ring depth 16; L0 overwrite guard = single super1[t-16] check.
// Weights in LDS. fp16 MFMA 16x16x32, fragment-major operands.
// ---------------------------------------------------------------------------

#define B_   64
#define T_   512
#define I_   256
#define H_   768
#define G4H  3072

constexpr size_t BTH = (size_t)B_ * T_ * H_;   // 25165824
constexpr size_t BH  = (size_t)B_ * H_;        // 49152

using f16_t = _Float16;
using f16x8 = __attribute__((ext_vector_type(8))) _Float16;
using f32x4 = __attribute__((ext_vector_type(4))) float;
typedef unsigned long long u64;

#define MFMA(a, b, c) __builtin_amdgcn_mfma_f32_16x16x32_f16((a), (b), (c), 0, 0, 0)

// Ring: quantum u64 = 4 f16 units. addr = slot*98304 + ws*1024 + q*512 + b*8.
#define SLOT_STRIDE 98304    // 96*64*16 bytes
#define RING_SLOTS  16
#define RING_BYTES  (RING_SLOTS * SLOT_STRIDE)

// LDS partition (bytes): WL 0..98304 | pre 98304..132096 | bsL ..132224
#define SMEM_BYTES 132224

// ---------------------------------------------------------------------------
__global__ void k_packW(const float* __restrict__ src, f16_t* __restrict__ dst,
                        int K, int KC, int total) {
  int i = blockIdx.x * blockDim.x + threadIdx.x;
  int stride = gridDim.x * blockDim.x;
  for (; i < total; i += stride) {
    int e = i & 7;
    int lane = (i >> 3) & 63;
    int rest = i >> 9;          // ptile*KC + kc
    int kc = rest % KC;
    int ptile = rest / KC;
    int p = ptile * 16 + (lane & 15);
    int k = kc * 32 + (lane >> 4) * 8 + e;
    int r = (p & 3) * H_ + (p >> 2);
    dst[i] = (f16_t)src[(size_t)r * K + k];
  }
}

__global__ void k_packX(const float* __restrict__ x, f16_t* __restrict__ dst) {
  int i = blockIdx.x * blockDim.x + threadIdx.x;
  int stride = gridDim.x * blockDim.x;
  const int total = 4 * T_ * 8 * 64 * 8;  // 8,388,608
  for (; i < total; i += stride) {
    int e = i & 7;
    int lane = (i >> 3) & 63;
    int kc = (i >> 9) & 7;
    int t = (i >> 12) & 511;
    int mtile = i >> 21;
    int b = mtile * 16 + (lane & 15);
    int k = kc * 32 + (lane >> 4) * 8 + e;
    dst[i] = (f16_t)x[((size_t)b * T_ + t) * I_ + k];
  }
}

__global__ void k_bias(const float* __restrict__ bih, const float* __restrict__ bhh,
                       float* __restrict__ bsum) {
  int p = blockIdx.x * blockDim.x + threadIdx.x;
  if (p < G4H) {
    int r = (p & 3) * H_ + (p >> 2);
    bsum[p] = bih[r] + bhh[r];
  }
}

// Grid-stride zero (full coverage regardless of grid size).
__global__ void k_zero(int4* __restrict__ d, int n) {
  int stride = gridDim.x * blockDim.x;
  for (int i = blockIdx.x * blockDim.x + threadIdx.x; i < n; i += stride)
    d[i] = make_int4(0, 0, 0, 0);
}

__device__ __forceinline__ float sigf(float v) {
  return __builtin_amdgcn_rcpf(1.0f + __builtin_amdgcn_exp2f(v * -1.44269504f));
}
__device__ __forceinline__ float tanhf_fast(float v) {
  return 2.0f * __builtin_amdgcn_rcpf(1.0f + __builtin_amdgcn_exp2f(v * -2.88539008f)) - 1.0f;
}

__device__ __forceinline__ u64 ld_q(const u64* p) {
  return __hip_atomic_load(p, __ATOMIC_RELAXED, __HIP_MEMORY_SCOPE_AGENT);
}
__device__ __forceinline__ unsigned ld_flag(const int* p) {
  return (unsigned)__hip_atomic_load(p, __ATOMIC_RELAXED, __HIP_MEMORY_SCOPE_AGENT);
}

// Single-line super-flag spin (wave-uniform address -> 1 transaction/round).
__device__ __forceinline__ void wait_super(const int* p, unsigned tagv) {
  for (;;) {
    if (ld_flag(p) == tagv) return;
    __builtin_amdgcn_s_sleep(1);
  }
}

// One-shot burst (flag-guaranteed): per chunk i load q0,q1 for both mtiles,
// assemble f16x8 fragments, MFMA.
template <int KCW>
__device__ __forceinline__ void load_mfma(const char* sb, const int (&bA)[KCW],
                                          const f16_t* wl0, const f16_t* wl1,
                                          f32x4& a00, f32x4& a01, f32x4& a10,
                                          f32x4& a11) {
  u64 vA[KCW][2], vB[KCW][2];
#pragma unroll
  for (int i = 0; i < KCW; ++i) {
    const u64* p = (const u64*)(sb + bA[i]);
    vA[i][0] = ld_q(p);        // q0, mtile m0
    vA[i][1] = ld_q(p + 64);   // q1 (+512B)
    vB[i][0] = ld_q(p + 16);   // q0, mtile m0+1 (+128B)
    vB[i][1] = ld_q(p + 80);   // q1, mtile m0+1
  }
#pragma unroll
  for (int i = 0; i < KCW; ++i) {
    union { u64 q[2]; f16x8 f; } cA, cB;
    cA.q[0] = vA[i][0]; cA.q[1] = vA[i][1];
    cB.q[0] = vB[i][0]; cB.q[1] = vB[i][1];
    f16x8 w0 = *(const f16x8*)(wl0 + (size_t)i * 512);
    f16x8 w1 = *(const f16x8*)(wl1 + (size_t)i * 512);
    a00 = MFMA(cA.f, w0, a00);
    a01 = MFMA(cA.f, w1, a01);
    a10 = MFMA(cB.f, w0, a10);
    a11 = MFMA(cB.f, w1, a11);
  }
}

// ---------------------------------------------------------------------------
// Aggregator (one wave): for each t, detect all 96 per-WG flags == t+1, then
// post super[t] = t+1. Dedicated -> tight spin (no sleep) for fastest detect.
__device__ __forceinline__ void run_agg(const int* __restrict__ flags,
                                        int* __restrict__ sup) {
  if ((threadIdx.x >> 6) != 0) return;   // wave 0 only
  const int lane = threadIdx.x & 63;
  for (int t = 0; t < T_; ++t) {
    const int* f = flags + (size_t)t * 128 * 4;
    const unsigned want = (unsigned)(t + 1);
    for (;;) {
      unsigned v0 = ld_flag(f + lane * 4);
      unsigned v1 = (lane < 32) ? ld_flag(f + (64 + lane) * 4) : want;
      if (__all((v0 == want) & (v1 == want))) break;
    }
    asm volatile("s_waitcnt vmcnt(0)" ::: "memory");
    if (lane == 0)
      __hip_atomic_store(sup + (size_t)t * 4, (int)want, __ATOMIC_RELAXED,
                         __HIP_MEMORY_SCOPE_AGENT);
  }
}

// ---------------------------------------------------------------------------
// Persistent per-layer loop (r10 structure). 8 waves = mg(2) x kg(4);
// wave = 2x2 tile. L0: kg0 = x-GEMM (+ mg1: super1[t-16] ring guard);
// kg1-3 consume h0[t-1]. L1: kg0-1 consume h0[t], kg2-3 consume h1[t-1].
// Consumer release = super-flags (aggregated); producer per-WG flags feed
// only the aggregators.
template <int KCW, bool IS_L1>
__device__ __forceinline__ void run_layer(
    int ws, const f16_t* __restrict__ Xf, const f16_t* __restrict__ Wihf,
    const f16_t* __restrict__ Whhf, const float* __restrict__ bsum,
    char* __restrict__ ring0c, char* __restrict__ ring1c,
    int* __restrict__ flag0, int* __restrict__ flag1,
    int* __restrict__ sup0, int* __restrict__ sup1,
    float* __restrict__ out, char* smem) {
  f16_t* WL = (f16_t*)smem;                              // [4 kg][2 p][KCW][512]
  float (*pre)[64][33] = (float (*)[64][33])(smem + 98304);
  float* bsL = (float*)(smem + 132096);                  // [32]

  const int tid = threadIdx.x;
  const int wave = tid >> 6, lane = tid & 63;
  const int kg = wave & 3, mg = wave >> 2;
  const int laneo = lane * 8;
  const int pt0 = ws * 2, m0 = mg * 2;
  const int l15 = lane & 15, l4 = lane >> 4;

  if (tid < 32) bsL[tid] = bsum[ws * 32 + tid];

  // ---- stage W into LDS (mg==0 waves) ----
  if (mg == 0) {
    const f16_t* src;
    int KC, kc0;
    if constexpr (!IS_L1) {
      if (kg == 0) { src = Wihf; KC = 8;  kc0 = 0; }
      else         { src = Whhf; KC = 24; kc0 = (kg - 1) * 8; }
    } else {
      if (kg < 2)  { src = Wihf; KC = 24; kc0 = kg * 12; }
      else         { src = Whhf; KC = 24; kc0 = (kg - 2) * 12; }
    }
#pragma unroll
    for (int p = 0; p < 2; ++p)
#pragma unroll
      for (int i = 0; i < KCW; ++i)
        *(uint4*)(WL + ((size_t)((kg * 2 + p) * KCW + i)) * 512 + laneo) =
            *(const uint4*)(src + ((size_t)(pt0 + p) * KC + kc0 + i) * 512 + laneo);
  }

  // Consumer chunk start (32-unit chunks of the source h vector).
  int kcs = 0;
  if constexpr (!IS_L1) kcs = (kg - 1) * 8;      // valid for kg>=1
  else                  kcs = (kg < 2) ? kg * 12 : (kg - 2) * 12;

  // Byte offset of chunk i's base quantum: producer ws'=(kcs+i)*4+l4,
  // batch row = m0*16+l15.
  int bA[KCW];
#pragma unroll
  for (int i = 0; i < KCW; ++i)
    bA[i] = ((kcs + i) * 4 + l4) * 1024 + (m0 * 16 + l15) * 8;

  float c_reg = 0.f;
  const int u = tid & 7, b = tid >> 3;
  const int j = ws * 8 + u;
  char* myringc = IS_L1 ? ring1c : ring0c;
  int* myflag = IS_L1 ? flag1 : flag0;
  const f16_t* wl0 = WL + (size_t)(kg * 2) * KCW * 512 + laneo;
  const f16_t* wl1 = wl0 + (size_t)KCW * 512;

  __syncthreads();

  for (int t = 0; t < T_; ++t) {
    f32x4 a00 = {0.f, 0.f, 0.f, 0.f};
    f32x4 a01 = {0.f, 0.f, 0.f, 0.f};
    f32x4 a10 = {0.f, 0.f, 0.f, 0.f};
    f32x4 a11 = {0.f, 0.f, 0.f, 0.f};

    if constexpr (!IS_L1) {
      if (kg == 0) {
        // ring guard: before publishing h0[t] over h0[t-16]'s slot, all L1
        // WGs must be past step t-16 (single super-flag check, off-path).
        if (mg == 1 && t >= RING_SLOTS)
          wait_super(sup1 + (size_t)(t - RING_SLOTS) * 4,
                     (unsigned)(t - RING_SLOTS + 1));
        // x_t @ Wih0^T (no recurrence dependency)
        const f16_t* A0 = Xf + ((size_t)m0 * T_ + t) * 4096 + laneo;
        const f16_t* A1 = A0 + (size_t)T_ * 4096;
#pragma unroll
        for (int i = 0; i < KCW; ++i) {
          f16x8 x0 = *(const f16x8*)(A0 + (size_t)i * 512);
          f16x8 x1 = *(const f16x8*)(A1 + (size_t)i * 512);
          f16x8 w0 = *(const f16x8*)(wl0 + (size_t)i * 512);
          f16x8 w1 = *(const f16x8*)(wl1 + (size_t)i * 512);
          a00 = MFMA(x0, w0, a00);
          a01 = MFMA(x0, w1, a01);
          a10 = MFMA(x1, w0, a10);
          a11 = MFMA(x1, w1, a11);
        }
      } else if (t >= 1) {
        wait_super(sup0 + (size_t)(t - 1) * 4, (unsigned)t);
        const char* sb = ring0c + (size_t)((t - 1) & (RING_SLOTS - 1)) * SLOT_STRIDE;
        load_mfma<KCW>(sb, bA, wl0, wl1, a00, a01, a10, a11);
      }
    } else {
      const int srcstep = (kg < 2) ? t : t - 1;
      if (srcstep >= 0) {
        const unsigned tg = (unsigned)(srcstep + 1);
        wait_super(((kg < 2) ? sup0 : sup1) + (size_t)srcstep * 4, tg);
        const char* sb = ((kg < 2) ? ring0c : ring1c) +
                         (size_t)(srcstep & (RING_SLOTS - 1)) * SLOT_STRIDE;
        load_mfma<KCW>(sb, bA, wl0, wl1, a00, a01, a10, a11);
      }
    }

    // ---- partial-sum exchange (C layout: col=lane&15, row=l4*4+r) ----
#pragma unroll
    for (int r = 0; r < 4; ++r) {
      pre[kg][m0 * 16 + l4 * 4 + r][l15]           = a00[r];
      pre[kg][m0 * 16 + l4 * 4 + r][16 + l15]      = a01[r];
      pre[kg][m0 * 16 + 16 + l4 * 4 + r][l15]      = a10[r];
      pre[kg][m0 * 16 + 16 + l4 * 4 + r][16 + l15] = a11[r];
    }
    __syncthreads();

    // ---- gate phase: thread = (u = tid&7, b = tid>>3) ----
    float h;
    {
      float g0 = pre[0][b][4 * u + 0] + pre[1][b][4 * u + 0] + pre[2][b][4 * u + 0] + pre[3][b][4 * u + 0] + bsL[4 * u + 0];
      float g1 = pre[0][b][4 * u + 1] + pre[1][b][4 * u + 1] + pre[2][b][4 * u + 1] + pre[3][b][4 * u + 1] + bsL[4 * u + 1];
      float g2 = pre[0][b][4 * u + 2] + pre[1][b][4 * u + 2] + pre[2][b][4 * u + 2] + pre[3][b][4 * u + 2] + bsL[4 * u + 2];
      float g3 = pre[0][b][4 * u + 3] + pre[1][b][4 * u + 3] + pre[2][b][4 * u + 3] + pre[3][b][4 * u + 3] + bsL[4 * u + 3];
      float ig = sigf(g0), fg = sigf(g1), gg = tanhf_fast(g2), og = sigf(g3);
      c_reg = fg * c_reg + ig * gg;
      h = og * tanhf_fast(c_reg);

      // ring publish: gather 4 units via shfl, u%4==0 stores one u64 quantum.
      unsigned hb = (unsigned)__builtin_bit_cast(unsigned short, (f16_t)h);
      unsigned n1 = (unsigned)__shfl((int)hb, lane + 1);
      unsigned n2 = (unsigned)__shfl((int)hb, lane + 2);
      unsigned n3 = (unsigned)__shfl((int)hb, lane + 3);
      if ((u & 3) == 0) {
        u64 val = (u64)(hb | (n1 << 16)) | ((u64)(n2 | (n3 << 16)) << 32);
        u64* dst = (u64*)(myringc +
                          (size_t)(t & (RING_SLOTS - 1)) * SLOT_STRIDE +
                          (size_t)ws * 1024 + (u >> 2) * 512 + (size_t)b * 8);
        __hip_atomic_store(dst, val, __ATOMIC_RELAXED, __HIP_MEMORY_SCOPE_AGENT);
      }
    }
    // per-wave ack of own ring stores (parallel across waves), then publish.
    asm volatile("s_waitcnt vmcnt(0)" ::: "memory");
    __syncthreads();
    if (tid == 0)
      __hip_atomic_store(myflag + ((size_t)t * 128 + ws) * 4, t + 1,
                         __ATOMIC_RELAXED, __HIP_MEMORY_SCOPE_AGENT);

    // ---- deferred outputs (off critical path) ----
    if constexpr (IS_L1) {
      out[((size_t)b * T_ + t) * H_ + j] = h;  // ys
      if (t == T_ - 1) {
        out[BTH + BH + (size_t)b * H_ + j] = h;
        out[BTH + 3 * BH + (size_t)b * H_ + j] = c_reg;
      }
    } else {
      if (t == T_ - 1) {
        out[BTH + (size_t)b * H_ + j] = h;
        out[BTH + 2 * BH + (size_t)b * H_ + j] = c_reg;
      }
    }
  }
}

__launch_bounds__(512, 1)
__global__ void k_lstm(const f16_t* __restrict__ Xf,
                       const f16_t* __restrict__ Wih0f, const f16_t* __restrict__ Whh0f,
                       const f16_t* __restrict__ Wih1f, const f16_t* __restrict__ Whh1f,
                       const float* __restrict__ bsum0, const float* __restrict__ bsum1,
                       char* __restrict__ ring0c, char* __restrict__ ring1c,
                       int* __restrict__ flag0, int* __restrict__ flag1,
                       int* __restrict__ sup0, int* __restrict__ sup1,
                       float* __restrict__ out) {
  extern __shared__ char smem[];
  const int wg = blockIdx.x;
  if (wg < 96)
    run_layer<8, false>(wg, Xf, Wih0f, Whh0f, bsum0, ring0c, ring1c,
                        flag0, flag1, sup0, sup1, out, smem);
  else if (wg < 192)
    run_layer<12, true>(wg - 96, Xf, Wih1f, Whh1f, bsum1, ring0c, ring1c,
                        flag0, flag1, sup0, sup1, out, smem);
  else if (wg == 192)
    run_agg(flag0, sup0);
  else
    run_agg(flag1, sup1);
}

// ---------------------------------------------------------------------------
extern "C" void kernel_launch(void* const* d_in, const int* in_sizes, int n_in,
                              void* d_out, int out_size, void* d_ws, size_t ws_size,
                              hipStream_t stream) {
  const float* x    = (const float*)d_in[0];
  const float* wih0 = (const float*)d_in[1];
  const float* whh0 = (const float*)d_in[2];
  const float* bih0 = (const float*)d_in[3];
  const float* bhh0 = (const float*)d_in[4];
  const float* wih1 = (const float*)d_in[5];
  const float* whh1 = (const float*)d_in[6];
  const float* bih1 = (const float*)d_in[7];
  const float* bhh1 = (const float*)d_in[8];
  float* out = (float*)d_out;

  char* base = (char*)d_ws;
  size_t off = 0;
  auto take = [&](size_t bytes) -> char* {
    char* r = base + off;
    off = (off + bytes + 255) & ~(size_t)255;
    return r;
  };
  f16_t* Wih0f = (f16_t*)take((size_t)G4H * I_ * 2);
  f16_t* Whh0f = (f16_t*)take((size_t)G4H * H_ * 2);
  f16_t* Wih1f = (f16_t*)take((size_t)G4H * H_ * 2);
  f16_t* Whh1f = (f16_t*)take((size_t)G4H * H_ * 2);
  f16_t* Xf    = (f16_t*)take((size_t)4 * T_ * 8 * 64 * 8 * 2);
  float* bsum0 = (float*)take((size_t)G4H * 4);
  float* bsum1 = (float*)take((size_t)G4H * 4);
  // rings (flag-gated; no zero needed) + per-WG flags + super-flags (zeroed)
  char* ring0c = take(RING_BYTES);
  char* ring1c = take(RING_BYTES);
  const size_t flagBytes = (size_t)T_ * 128 * 16;        // 1 MB each
  const size_t supBytes  = (size_t)T_ * 16;              // 8 KB each
  char* fl = take(2 * flagBytes + 2 * supBytes);
  int* flag0 = (int*)fl;
  int* flag1 = flag0 + (size_t)T_ * 128 * 4;
  int* sup0  = flag1 + (size_t)T_ * 128 * 4;
  int* sup1  = sup0 + (size_t)T_ * 4;
  const size_t zeroBytes = 2 * flagBytes + 2 * supBytes;

  hipFuncSetAttribute(reinterpret_cast<const void*>(k_lstm),
                      hipFuncAttributeMaxDynamicSharedMemorySize, SMEM_BYTES);

  k_packW<<<768, 256, 0, stream>>>(wih0, Wih0f, I_, 8, G4H * I_);
  k_packW<<<2048, 256, 0, stream>>>(whh0, Whh0f, H_, 24, G4H * H_);
  k_packW<<<2048, 256, 0, stream>>>(wih1, Wih1f, H_, 24, G4H * H_);
  k_packW<<<2048, 256, 0, stream>>>(whh1, Whh1f, H_, 24, G4H * H_);
  k_packX<<<4096, 256, 0, stream>>>(x, Xf);
  k_bias<<<12, 256, 0, stream>>>(bih0, bhh0, bsum0);
  k_bias<<<12, 256, 0, stream>>>(bih1, bhh1, bsum1);
  k_zero<<<520, 256, 0, stream>>>((int4*)fl, (int)(zeroBytes / 16));

  k_lstm<<<194, 512, SMEM_BYTES, stream>>>(Xf, Wih0f, Whh0f, Wih1f, Whh1f,
                                           bsum0, bsum1, ring0c, ring1c,
                                           flag0, flag1, sup0, sup1, out);
}